// Round 2
// baseline (106.201 us; speedup 1.0000x reference)
//
#include <hip/hip_runtime.h>

// Elman RNN, T=2e6, I=2, H=30, O=1 — fully-folded MFMA chunked scan.
// r13: depth-halving. r12 (no LDS/barriers) left kernel <42us per rocprof
// (not in top-5; fills at 43us dominate the timed graph). Model: ~480
// cyc/chain-step vs ~150-200 cyc dependency floor => latency-bound at
// 2 waves/SIMD. Fix: CHUNK_LEN 64->32 (depth 80->48: 16 burn + 32 main),
// 1024 blocks, launch_bounds(256,4) -> 4 waves/SIMD. Work +20% (burn
// fraction 33%), wall depth x0.6, concurrency x2. Step logic unchanged.
// Per chain-step one padded 32x32 matvec via 4x mfma_f32_16x16x16_f16:
//   A = [SC*W_hh | SC*W_ih ; W_fc 0 ; 0], B rows 0-29 = h_{t-1} (f16),
//   rows 30,31 = x_t; C = [SC*(b_ih+b_hh); b_fc; 0]
// => D rows 0-29 = SC*pre_t, row 30 = out[t-1] (g3 lanes' d_b[2]).
// SC = 2*log2(e): tanh(p) = 1 - 2*rcp(1 + exp2(SC*p)).

#define T_LEN     2000000
#define HID       30
#define CHUNK_LEN 32
#define BURN      15           // burn iters = 16 (windows 0-1)
#define NBLOCK    1024         // 1024 blk x 64 chunks = 65536 >= 62500
#define WSTEPS    8
#define NWIN      6            // 2 burn + 4 main (48 steps)

typedef __attribute__((ext_vector_type(4))) _Float16 half4;
typedef __attribute__((ext_vector_type(2))) __fp16   fp16x2;  // pkrtz type
typedef __attribute__((ext_vector_type(4))) float    float4v;

union h4u { half4 v4; fp16x2 v2[2]; unsigned u2[2]; };
union h2u { fp16x2 v; unsigned u; };

// issue next window's x loads into nxt[] (all lanes; same-cl lanes dup
// addresses -> coalesced/broadcast; clamp keeps every lane in bounds).
#define PREFETCH(O) {                                                        \
    _Pragma("unroll")                                                        \
    for (int s = 0; s < WSTEPS; ++s) {                                       \
        int tt = wbase + (O) * WSTEPS + s;                                   \
        tt = tt < 0 ? 0 : (tt >= T_LEN ? T_LEN - 1 : tt);                    \
        nxt[s] = xf2[tt];                                                    \
    }                                                                        \
}

// convert the landed window to packed f16 pairs (compiler inserts the
// counted vmcnt wait here; out[] stores stay outstanding past it)
#define CONVERT() {                                                          \
    _Pragma("unroll")                                                        \
    for (int s = 0; s < WSTEPS; ++s) {                                       \
        h2u c; c.v = __builtin_amdgcn_cvt_pkrtz(nxt[s].x, nxt[s].y);         \
        xcur[s] = c.u;                                                       \
    }                                                                        \
}

// one chain-step; x value comes in as a register (XC)
#define STEP_BODY(XC, MASKQ, STOREQ)                                         \
{                                                                            \
    float th[8];                                                             \
    _Pragma("unroll")                                                        \
    for (int i = 0; i < 4; ++i) {                                            \
        th[i]   = 1.f - 2.f * __builtin_amdgcn_rcpf(1.f + __builtin_amdgcn_exp2f(d_t[i])); \
        th[4+i] = 1.f - 2.f * __builtin_amdgcn_rcpf(1.f + __builtin_amdgcn_exp2f(d_b[i])); \
    }                                                                        \
    if (MASKQ) {                                                             \
        const float m = (t_cur >= 1) ? 1.f : 0.f;                            \
        _Pragma("unroll")                                                    \
        for (int i = 0; i < 8; ++i) th[i] *= m;                              \
    }                                                                        \
    h4u b0, b1;                                                              \
    b0.v2[0] = __builtin_amdgcn_cvt_pkrtz(th[0], th[1]);                     \
    b0.v2[1] = __builtin_amdgcn_cvt_pkrtz(th[2], th[3]);                     \
    b1.v2[0] = __builtin_amdgcn_cvt_pkrtz(th[4], th[5]);                     \
    b1.v2[1] = __builtin_amdgcn_cvt_pkrtz(th[6], th[7]);                     \
    if (g3) b1.u2[1] = (XC);                                                 \
    d_t = __builtin_amdgcn_mfma_f32_16x16x16f16(a_t0, b0.v4, cT, 0, 0, 0);   \
    d_b = __builtin_amdgcn_mfma_f32_16x16x16f16(a_b0, b0.v4, cB, 0, 0, 0);   \
    d_t = __builtin_amdgcn_mfma_f32_16x16x16f16(a_t1, b1.v4, d_t, 0, 0, 0);  \
    d_b = __builtin_amdgcn_mfma_f32_16x16x16f16(a_b1, b1.v4, d_b, 0, 0, 0);  \
    if (STOREQ) {                                                            \
        const int ta = t_cur - 1;                                            \
        if (g3 && ta < my_end) out[ta] = d_b[2];                             \
    }                                                                        \
    ++t_cur;                                                                 \
}

__global__ __launch_bounds__(256, 4)
void rnn_mfma_kernel(const float* __restrict__ x,
                     const float* __restrict__ W_ih,
                     const float* __restrict__ W_hh,
                     const float* __restrict__ b_ih,
                     const float* __restrict__ b_hh,
                     const float* __restrict__ W_fc,
                     const float* __restrict__ b_fc,
                     float* __restrict__ out)
{
    const int tid  = threadIdx.x;
    const int wave = tid >> 6;          // 0..3
    const int lane = tid & 63;
    const int g    = lane >> 4;         // reg-group 0..3
    const int cl   = lane & 15;         // A-row (top) / chunk column
    const bool g3  = (g == 3);

    const int chunk = blockIdx.x * 64 + wave * 16 + cl;  // global chunk
    const int wbase = chunk * CHUNK_LEN - BURN;          // first x time
    const float2* __restrict__ xf2 = (const float2*)x;

    const float SC = 2.0f * 1.44269504088896340736f;   // 2*log2(e)

    // ---- static A fragments (f16), padded per the header comment ----
    half4 a_t0, a_t1, a_b0, a_b1;
#pragma unroll
    for (int i = 0; i < 4; ++i) {
        const int k0 = 4*g + i;        // 0..15
        const int k1 = 16 + 4*g + i;   // 16..31
        const int mt = cl;             // rows 0..15
        const int mb = 16 + cl;        // rows 16..31

        a_t0[i] = (_Float16)(SC * W_hh[mt*HID + k0]);
        float v_t1;
        if (k1 < HID)        v_t1 = SC * W_hh[mt*HID + k1];
        else if (k1 == HID)  v_t1 = SC * W_ih[mt*2 + 0];
        else                 v_t1 = SC * W_ih[mt*2 + 1];
        a_t1[i] = (_Float16)v_t1;

        float v_b0, v_b1;
        if (mb < HID) {
            v_b0 = SC * W_hh[mb*HID + k0];
            if (k1 < HID)        v_b1 = SC * W_hh[mb*HID + k1];
            else if (k1 == HID)  v_b1 = SC * W_ih[mb*2 + 0];
            else                 v_b1 = SC * W_ih[mb*2 + 1];
        } else if (mb == HID) {        // FC row: unscaled, x-cols zero
            v_b0 = W_fc[k0];
            v_b1 = (k1 < HID) ? W_fc[k1] : 0.f;
        } else {                       // row 31: zero
            v_b0 = 0.f; v_b1 = 0.f;
        }
        a_b0[i] = (_Float16)v_b0;
        a_b1[i] = (_Float16)v_b1;
    }

    // ---- C operands: scaled biases; row30 = b_fc; row31 = 0 ----
    float4v cT, cB;
#pragma unroll
    for (int i = 0; i < 4; ++i) {
        const int rt  = 4*g + i;
        const int rb2 = 16 + 4*g + i;
        cT[i] = SC * (b_ih[rt] + b_hh[rt]);
        cB[i] = (rb2 < HID)  ? SC * (b_ih[rb2] + b_hh[rb2])
              : (rb2 == HID) ? b_fc[0] : 0.f;
    }

    int my_end = chunk * CHUNK_LEN + CHUNK_LEN;
    if (my_end > T_LEN) my_end = T_LEN;

    __builtin_amdgcn_sched_barrier(0);

    float4v d_t = {0.f,0.f,0.f,0.f}, d_b = {0.f,0.f,0.f,0.f};

    int t_cur = wbase;                  // time of x consumed this step

    float2   nxt[WSTEPS];               // in-flight window (float2)
    unsigned xcur[WSTEPS];              // current window (packed f16 pairs)

    PREFETCH(0)

    // ---- burn windows 0-1 (16 steps, h masked while t_cur < 1) ----
#pragma clang loop unroll(disable)
    for (int o = 0; o < 2; ++o) {
        CONVERT()
        PREFETCH(o + 1)
#pragma unroll
        for (int s = 0; s < WSTEPS; ++s) {
            STEP_BODY(xcur[s], true, false)
        }
    }

    // ---- main windows 2-5 (32 steps, store out[t_cur-1]) ----
#pragma clang loop unroll(disable)
    for (int o = 2; o < NWIN; ++o) {
        CONVERT()
        if (o < NWIN - 1) { PREFETCH(o + 1) }
#pragma unroll
        for (int s = 0; s < WSTEPS; ++s) {
            STEP_BODY(xcur[s], false, true)
        }
    }
}

extern "C" void kernel_launch(void* const* d_in, const int* in_sizes, int n_in,
                              void* d_out, int out_size, void* d_ws, size_t ws_size,
                              hipStream_t stream)
{
    const float* x    = (const float*)d_in[0];
    const float* W_ih = (const float*)d_in[1];
    const float* W_hh = (const float*)d_in[2];
    const float* b_ih = (const float*)d_in[3];
    const float* b_hh = (const float*)d_in[4];
    const float* W_fc = (const float*)d_in[5];
    const float* b_fc = (const float*)d_in[6];
    float* out = (float*)d_out;

    // 1024 blocks x 4 waves x 16 chunks = 65536 chunks (>= 62500);
    // 4 blocks/CU = 4 waves/SIMD; no LDS, no intra-block coupling.
    rnn_mfma_kernel<<<NBLOCK, 256, 0, stream>>>(x, W_ih, W_hh, b_ih, b_hh,
                                                W_fc, b_fc, out);
}

// Round 5
// 101.461 us; speedup vs baseline: 1.0467x; 1.0467x over previous
//
#include <hip/hip_runtime.h>

// Elman RNN, T=2e6, I=2, H=30, O=1 — fully-folded MFMA chunked scan.
// r14 (2nd resubmit — r3/r4 benches never acquired a GPU):
// (a) revert r13's depth-halving — r13 proved the kernel ISSUE-bound
// (+20% work -> +4.2us, exactly tracking work, not depth), so back to
// CHUNK_LEN=64 / 512 blocks / 2 waves/SIMD (r12's measured geometry).
// (b) fuse K-split: 4x mfma_f32_16x16x16f16 -> 2x mfma_f32_16x16x32_f16.
// gfx950 x32 frag layout is the SPLIT one (halves 0-3: k=4g+i, halves
// 4-7: k=16+4g+i — per learn_hip m162 tr_b16 address map / HK usage), so
// a_t0||a_t1 and b0||b1 concatenate directly; C/D layout unchanged.
// Halves MFMA issue, removes the 2-chained MFMA dependency, avoids any
// CDNA4 legacy-shape penalty.
// Per chain-step one padded 32x32 matvec via 2x mfma_f32_16x16x32_f16:
//   A = [SC*W_hh | SC*W_ih ; W_fc 0 ; 0], B rows 0-29 = h_{t-1} (f16),
//   rows 30,31 = x_t; C = [SC*(b_ih+b_hh); b_fc; 0]
// => D rows 0-29 = SC*pre_t, row 30 = out[t-1] (g3 lanes' d_b[2]).
// SC = 2*log2(e): tanh(p) = 1 - 2*rcp(1 + exp2(SC*p)).

#define T_LEN     2000000
#define HID       30
#define CHUNK_LEN 64
#define BURN      15           // burn iters = 16 (windows 0-1)
#define NBLOCK    512          // 512 blk x 64 chunks = 32768 >= 31250
#define WSTEPS    8
#define NWIN      10           // 2 burn + 8 main

typedef __attribute__((ext_vector_type(8))) _Float16 half8;
typedef __attribute__((ext_vector_type(2))) __fp16   fp16x2;  // pkrtz type
typedef __attribute__((ext_vector_type(4))) float    float4v;

union h8u { half8 v8; fp16x2 v2[4]; unsigned u2[4]; };
union h2u { fp16x2 v; unsigned u; };

// issue next window's x loads into nxt[] (all lanes; same-cl lanes dup
// addresses -> coalesced/broadcast; clamp keeps every lane in bounds).
#define PREFETCH(O) {                                                        \
    _Pragma("unroll")                                                        \
    for (int s = 0; s < WSTEPS; ++s) {                                       \
        int tt = wbase + (O) * WSTEPS + s;                                   \
        tt = tt < 0 ? 0 : (tt >= T_LEN ? T_LEN - 1 : tt);                    \
        nxt[s] = xf2[tt];                                                    \
    }                                                                        \
}

// convert the landed window to packed f16 pairs (compiler inserts the
// counted vmcnt wait here; out[] stores stay outstanding past it)
#define CONVERT() {                                                          \
    _Pragma("unroll")                                                        \
    for (int s = 0; s < WSTEPS; ++s) {                                       \
        h2u c; c.v = __builtin_amdgcn_cvt_pkrtz(nxt[s].x, nxt[s].y);         \
        xcur[s] = c.u;                                                       \
    }                                                                        \
}

// one chain-step; x value comes in as a register (XC)
#define STEP_BODY(XC, MASKQ, STOREQ)                                         \
{                                                                            \
    float th[8];                                                             \
    _Pragma("unroll")                                                        \
    for (int i = 0; i < 4; ++i) {                                            \
        th[i]   = 1.f - 2.f * __builtin_amdgcn_rcpf(1.f + __builtin_amdgcn_exp2f(d_t[i])); \
        th[4+i] = 1.f - 2.f * __builtin_amdgcn_rcpf(1.f + __builtin_amdgcn_exp2f(d_b[i])); \
    }                                                                        \
    if (MASKQ) {                                                             \
        const float m = (t_cur >= 1) ? 1.f : 0.f;                            \
        _Pragma("unroll")                                                    \
        for (int i = 0; i < 8; ++i) th[i] *= m;                              \
    }                                                                        \
    h8u b;                                                                   \
    b.v2[0] = __builtin_amdgcn_cvt_pkrtz(th[0], th[1]);                      \
    b.v2[1] = __builtin_amdgcn_cvt_pkrtz(th[2], th[3]);                      \
    b.v2[2] = __builtin_amdgcn_cvt_pkrtz(th[4], th[5]);                      \
    b.v2[3] = __builtin_amdgcn_cvt_pkrtz(th[6], th[7]);                      \
    if (g3) b.u2[3] = (XC);                                                  \
    d_t = __builtin_amdgcn_mfma_f32_16x16x32_f16(a_t.v8, b.v8, cT, 0, 0, 0); \
    d_b = __builtin_amdgcn_mfma_f32_16x16x32_f16(a_b.v8, b.v8, cB, 0, 0, 0); \
    if (STOREQ) {                                                            \
        const int ta = t_cur - 1;                                            \
        if (g3 && ta < my_end) out[ta] = d_b[2];                             \
    }                                                                        \
    ++t_cur;                                                                 \
}

__global__ __launch_bounds__(256, 2)
void rnn_mfma_kernel(const float* __restrict__ x,
                     const float* __restrict__ W_ih,
                     const float* __restrict__ W_hh,
                     const float* __restrict__ b_ih,
                     const float* __restrict__ b_hh,
                     const float* __restrict__ W_fc,
                     const float* __restrict__ b_fc,
                     float* __restrict__ out)
{
    const int tid  = threadIdx.x;
    const int wave = tid >> 6;          // 0..3
    const int lane = tid & 63;
    const int g    = lane >> 4;         // reg-group 0..3
    const int cl   = lane & 15;         // A-row (top) / chunk column
    const bool g3  = (g == 3);

    const int chunk = blockIdx.x * 64 + wave * 16 + cl;  // global chunk
    const int wbase = chunk * CHUNK_LEN - BURN;          // first x time
    const float2* __restrict__ xf2 = (const float2*)x;

    const float SC = 2.0f * 1.44269504088896340736f;   // 2*log2(e)

    // ---- static A fragments (f16): halves 0-3 = k0 (k=4g+i),
    //      halves 4-7 = k1 (k=16+4g+i) — x32 split frag layout ----
    h8u a_t, a_b;
#pragma unroll
    for (int i = 0; i < 4; ++i) {
        const int k0 = 4*g + i;        // 0..15
        const int k1 = 16 + 4*g + i;   // 16..31
        const int mt = cl;             // rows 0..15
        const int mb = 16 + cl;        // rows 16..31

        a_t.v8[i] = (_Float16)(SC * W_hh[mt*HID + k0]);
        float v_t1;
        if (k1 < HID)        v_t1 = SC * W_hh[mt*HID + k1];
        else if (k1 == HID)  v_t1 = SC * W_ih[mt*2 + 0];
        else                 v_t1 = SC * W_ih[mt*2 + 1];
        a_t.v8[4+i] = (_Float16)v_t1;

        float v_b0, v_b1;
        if (mb < HID) {
            v_b0 = SC * W_hh[mb*HID + k0];
            if (k1 < HID)        v_b1 = SC * W_hh[mb*HID + k1];
            else if (k1 == HID)  v_b1 = SC * W_ih[mb*2 + 0];
            else                 v_b1 = SC * W_ih[mb*2 + 1];
        } else if (mb == HID) {        // FC row: unscaled, x-cols zero
            v_b0 = W_fc[k0];
            v_b1 = (k1 < HID) ? W_fc[k1] : 0.f;
        } else {                       // row 31: zero
            v_b0 = 0.f; v_b1 = 0.f;
        }
        a_b.v8[i]   = (_Float16)v_b0;
        a_b.v8[4+i] = (_Float16)v_b1;
    }

    // ---- C operands: scaled biases; row30 = b_fc; row31 = 0 ----
    float4v cT, cB;
#pragma unroll
    for (int i = 0; i < 4; ++i) {
        const int rt  = 4*g + i;
        const int rb2 = 16 + 4*g + i;
        cT[i] = SC * (b_ih[rt] + b_hh[rt]);
        cB[i] = (rb2 < HID)  ? SC * (b_ih[rb2] + b_hh[rb2])
              : (rb2 == HID) ? b_fc[0] : 0.f;
    }

    int my_end = chunk * CHUNK_LEN + CHUNK_LEN;
    if (my_end > T_LEN) my_end = T_LEN;

    __builtin_amdgcn_sched_barrier(0);

    float4v d_t = {0.f,0.f,0.f,0.f}, d_b = {0.f,0.f,0.f,0.f};

    int t_cur = wbase;                  // time of x consumed this step

    float2   nxt[WSTEPS];               // in-flight window (float2)
    unsigned xcur[WSTEPS];              // current window (packed f16 pairs)

    PREFETCH(0)

    // ---- burn windows 0-1 (16 steps, h masked while t_cur < 1) ----
#pragma clang loop unroll(disable)
    for (int o = 0; o < 2; ++o) {
        CONVERT()
        PREFETCH(o + 1)
#pragma unroll
        for (int s = 0; s < WSTEPS; ++s) {
            STEP_BODY(xcur[s], true, false)
        }
    }

    // ---- main windows 2-9 (64 steps, store out[t_cur-1]) ----
#pragma clang loop unroll(disable)
    for (int o = 2; o < NWIN; ++o) {
        CONVERT()
        if (o < NWIN - 1) { PREFETCH(o + 1) }
#pragma unroll
        for (int s = 0; s < WSTEPS; ++s) {
            STEP_BODY(xcur[s], false, true)
        }
    }
}

extern "C" void kernel_launch(void* const* d_in, const int* in_sizes, int n_in,
                              void* d_out, int out_size, void* d_ws, size_t ws_size,
                              hipStream_t stream)
{
    const float* x    = (const float*)d_in[0];
    const float* W_ih = (const float*)d_in[1];
    const float* W_hh = (const float*)d_in[2];
    const float* b_ih = (const float*)d_in[3];
    const float* b_hh = (const float*)d_in[4];
    const float* W_fc = (const float*)d_in[5];
    const float* b_fc = (const float*)d_in[6];
    float* out = (float*)d_out;

    // 512 blocks x 4 waves x 16 chunks = 32768 chunks (>= 31250);
    // 2 blocks/CU = 2 waves/SIMD; no LDS, no intra-block coupling.
    rnn_mfma_kernel<<<NBLOCK, 256, 0, stream>>>(x, W_ih, W_hh, b_ih, b_hh,
                                                W_fc, b_fc, out);
}